// Round 1
// 1015.350 us; speedup vs baseline: 1.1914x; 1.1914x over previous
//
#include <hip/hip_runtime.h>
#include <stdint.h>

// ---------------------------------------------------------------------------
// FakeNewsModel: 3-layer GraphSAGE (mean agg), N=50000, E=1.6M, width 64.
// Round 4: k_project rewritten as thread-per-node with scalar (uniform) W-row
// loads and 64 fp32 accumulators. Old version was VMEM-latency bound at 488us
// (5% VALUBusy, 2.6% HBM): ~1000 tiny 4B W loads per thread. New version:
// W row index is wave-uniform -> s_load batches; x loads are 16B ushort8 with
// explicit double-buffering. Everything else identical to the passing kernel.
//   k_detect  -> flags[0]=floats-are-bf16?, flags[1]=ints-are-int64?
//   CSR build -> memset(cnt), k_deg, k_scan1/2/3, k_scatter
//   k_project -> x0 = concat(xc@Wp+bp, xs@Ws+bs)  (fp32 h-table)
//   k_layer x3 -> relu(mean-agg@Wl + bl + x@Wr); layer 3 fuses [64,2] head.
// ---------------------------------------------------------------------------

typedef __attribute__((ext_vector_type(8))) unsigned short u16x8;
typedef __attribute__((ext_vector_type(4))) float f32x4;

static __device__ __forceinline__ float bf2f(unsigned short u) {
  union { unsigned int i; float f; } v;
  v.i = ((unsigned int)u) << 16;
  return v.f;
}

static __device__ __forceinline__ unsigned short f2bf(float f) {
  union { float f; unsigned int i; } v;
  v.f = f;
  unsigned int u = v.i;
  unsigned int r = (u + 0x7FFFu + ((u >> 16) & 1u)) >> 16;  // RNE
  return (unsigned short)r;
}

template <bool BF>
static __device__ __forceinline__ float ldf(const void* p, long long i) {
  if (BF) return bf2f(((const unsigned short*)p)[i]);
  return ((const float*)p)[i];
}

// 8 consecutive floats starting at element idx (16B-aligned in bf16 world).
template <bool BF>
static __device__ __forceinline__ void load8(const void* p, long long idx,
                                             float* out) {
  if (BF) {
    u16x8 v = *(const u16x8*)((const unsigned short*)p + idx);
#pragma unroll
    for (int j = 0; j < 8; ++j) out[j] = bf2f(v[j]);
  } else {
    f32x4 a = *(const f32x4*)((const float*)p + idx);
    f32x4 b = *(const f32x4*)((const float*)p + idx + 4);
#pragma unroll
    for (int j = 0; j < 4; ++j) {
      out[j] = a[j];
      out[4 + j] = b[j];
    }
  }
}

static __device__ __forceinline__ int clampN(int v, int N) {
  return v < 0 ? 0 : (v >= N ? N - 1 : v);
}

// ---------------- dtype detection ----------------
__global__ void k_detect(const void* Wp, const int* ei, int* flags) {
  if (threadIdx.x == 0 && blockIdx.x == 0) {
    const unsigned short* w = (const unsigned short*)Wp;
    int bf = 1;
    for (int i = 0; i < 64; ++i) {
      float v = fabsf(bf2f(w[i]));
      if (!(v < 1.0f)) bf = 0;  // catches NaN too
    }
    flags[0] = bf;
    int i64 = 1;
    for (int i = 0; i < 32; ++i)
      if (ei[2 * i + 1] != 0) i64 = 0;
    flags[1] = i64;
  }
}

static __device__ __forceinline__ int edge_src(const int* ei, int e, int E,
                                               int i64) {
  return i64 ? ei[2 * (long long)e] : ei[e];
}
static __device__ __forceinline__ int edge_dst(const int* ei, int e, int E,
                                               int i64) {
  return i64 ? ei[2 * ((long long)E + e)] : ei[(long long)E + e];
}

// ---------------- CSR build ----------------

__global__ __launch_bounds__(256) void k_deg(const int* __restrict__ ei, int E,
                                             int N, int* __restrict__ cnt,
                                             const int* __restrict__ flags) {
  int e = blockIdx.x * 256 + threadIdx.x;
  if (e < E) {
    int d = clampN(edge_dst(ei, e, E, flags[1]), N);
    atomicAdd(&cnt[d], 1);
  }
}

__global__ __launch_bounds__(256) void k_scan1(const int* __restrict__ cnt,
                                               int* __restrict__ rowptr,
                                               int* __restrict__ bsum, int N) {
  __shared__ int sh[256];
  int t = threadIdx.x;
  int base = blockIdx.x * 1024 + t * 4;
  int v0 = 0, v1 = 0, v2 = 0, v3 = 0;
  if (base + 0 < N) v0 = cnt[base + 0];
  if (base + 1 < N) v1 = cnt[base + 1];
  if (base + 2 < N) v2 = cnt[base + 2];
  if (base + 3 < N) v3 = cnt[base + 3];
  int s = v0 + v1 + v2 + v3;
  sh[t] = s;
  __syncthreads();
  int acc = s;
  for (int off = 1; off < 256; off <<= 1) {
    int x = 0;
    if (t >= off) x = sh[t - off];
    __syncthreads();
    acc += x;
    sh[t] = acc;
    __syncthreads();
  }
  int run = acc - s;
  if (base + 0 < N) rowptr[base + 0] = run;
  run += v0;
  if (base + 1 < N) rowptr[base + 1] = run;
  run += v1;
  if (base + 2 < N) rowptr[base + 2] = run;
  run += v2;
  if (base + 3 < N) rowptr[base + 3] = run;
  run += v3;
  if (t == 255) bsum[blockIdx.x] = acc;
}

__global__ void k_scan2(int* __restrict__ bsum, int nb,
                        int* __restrict__ rowptr, int N) {
  if (threadIdx.x == 0 && blockIdx.x == 0) {
    int run = 0;
    for (int i = 0; i < nb; ++i) {
      int v = bsum[i];
      bsum[i] = run;
      run += v;
    }
    rowptr[N] = run;
  }
}

__global__ __launch_bounds__(256) void k_scan3(int* __restrict__ rowptr,
                                               int* __restrict__ cursor,
                                               const int* __restrict__ bsum,
                                               int N) {
  int i = blockIdx.x * 256 + threadIdx.x;
  if (i < N) {
    int v = rowptr[i] + bsum[i >> 10];
    rowptr[i] = v;
    cursor[i] = v;
  }
}

__global__ __launch_bounds__(256) void k_scatter(const int* __restrict__ ei,
                                                 int E, int N,
                                                 int* __restrict__ cursor,
                                                 int* __restrict__ colbuf,
                                                 const int* __restrict__ flags) {
  int e = blockIdx.x * 256 + threadIdx.x;
  if (e < E) {
    int i64 = flags[1];
    int s = clampN(edge_src(ei, e, E, i64), N);
    int d = clampN(edge_dst(ei, e, E, i64), N);
    int p = atomicAdd(&cursor[d], 1);
    if (p >= 0 && p < E) colbuf[p] = s;
  }
}

// ---------------- projection (v3: thread-per-node, scalar W loads) ----------
// One thread owns one node and all 64 output columns (32 content + 32 style)
// in fp32 registers. The W row index depends only on loop counters, so it is
// wave-uniform: the compiler selects s_load (scalar) loads, batched as
// dwordx8/x16, and feeds v_fma with one SGPR operand. x is loaded 16B at a
// time with explicit double-buffering so the next chunk's latency hides under
// the current chunk's 256 FMAs.
template <bool BF>
static __device__ void project_body(const void* __restrict__ xc,
                                    const void* __restrict__ xs,
                                    const void* __restrict__ Wp,
                                    const void* __restrict__ bp,
                                    const void* __restrict__ Ws,
                                    const void* __restrict__ bs,
                                    float* __restrict__ h0, int N) {
  int node = (int)blockIdx.x * 64 + (int)threadIdx.x;
  int nclamp = node < N ? node : (N - 1);

  float accc[32], accs[32];
#pragma unroll
  for (int o = 0; o < 32; ++o) {
    accc[o] = ldf<BF>(bp, o);
    accs[o] = ldf<BF>(bs, o);
  }

  // ---- content: [768] dot W_p[768,32] ----
  {
    long long xoff = (long long)nclamp * 768;
    float xv[8], xn[8];
    load8<BF>(xc, xoff, xv);
#pragma unroll 1
    for (int k = 0; k < 768; k += 8) {
      int kn = (k + 8 < 768) ? (k + 8) : 0;  // always-valid prefetch addr
      load8<BF>(xc, xoff + kn, xn);
#pragma unroll
      for (int j = 0; j < 8; ++j) {
        if (BF) {
          const unsigned int* wrow = (const unsigned int*)Wp + (k + j) * 16;
#pragma unroll
          for (int p = 0; p < 16; ++p) {
            unsigned int u = wrow[p];  // uniform -> s_load
            union { unsigned int i; float f; } c0, c1;
            c0.i = u << 16;
            c1.i = u & 0xFFFF0000u;
            accc[2 * p + 0] += xv[j] * c0.f;
            accc[2 * p + 1] += xv[j] * c1.f;
          }
        } else {
          const float* wrow = (const float*)Wp + (k + j) * 32;
#pragma unroll
          for (int o = 0; o < 32; ++o) accc[o] += xv[j] * wrow[o];
        }
      }
#pragma unroll
      for (int j = 0; j < 8; ++j) xv[j] = xn[j];
    }
  }

  // ---- style: [128] dot W_s[128,32] ----
  {
    long long soff = (long long)nclamp * 128;
    float xv[8], xn[8];
    load8<BF>(xs, soff, xv);
#pragma unroll 1
    for (int k = 0; k < 128; k += 8) {
      int kn = (k + 8 < 128) ? (k + 8) : 0;
      load8<BF>(xs, soff + kn, xn);
#pragma unroll
      for (int j = 0; j < 8; ++j) {
        if (BF) {
          const unsigned int* wrow = (const unsigned int*)Ws + (k + j) * 16;
#pragma unroll
          for (int p = 0; p < 16; ++p) {
            unsigned int u = wrow[p];  // uniform -> s_load
            union { unsigned int i; float f; } c0, c1;
            c0.i = u << 16;
            c1.i = u & 0xFFFF0000u;
            accs[2 * p + 0] += xv[j] * c0.f;
            accs[2 * p + 1] += xv[j] * c1.f;
          }
        } else {
          const float* wrow = (const float*)Ws + (k + j) * 32;
#pragma unroll
          for (int o = 0; o < 32; ++o) accs[o] += xv[j] * wrow[o];
        }
      }
#pragma unroll
      for (int j = 0; j < 8; ++j) xv[j] = xn[j];
    }
  }

  if (node < N) {
    float* orow = h0 + (long long)node * 64;
#pragma unroll
    for (int o = 0; o < 32; o += 4) {
      f32x4 vc, vs;
#pragma unroll
      for (int r = 0; r < 4; ++r) {
        vc[r] = accc[o + r];
        vs[r] = accs[o + r];
      }
      *(f32x4*)(orow + o) = vc;
      *(f32x4*)(orow + 32 + o) = vs;
    }
  }
}

__global__ __launch_bounds__(64) void k_project(
    const void* __restrict__ xc, const void* __restrict__ xs,
    const void* __restrict__ Wp, const void* __restrict__ bp,
    const void* __restrict__ Ws, const void* __restrict__ bs,
    float* __restrict__ h0, int N, const int* __restrict__ flags) {
  if (flags[0])
    project_body<true>(xc, xs, Wp, bp, Ws, bs, h0, N);
  else
    project_body<false>(xc, xs, Wp, bp, Ws, bs, h0, N);
}

// ---------------- SAGE layer ----------------
template <bool BF>
static __device__ void layer_body(const float* __restrict__ hin,
                                  const int* __restrict__ rowptr,
                                  const int* __restrict__ colbuf,
                                  const void* Wl, const void* bl,
                                  const void* Wr, float* __restrict__ hout,
                                  int N, int last, const void* Wo,
                                  const void* bo, void* outp) {
  int node = (int)((blockIdx.x * blockDim.x + threadIdx.x) >> 6);
  int lane = (int)(threadIdx.x & 63);
  if (node >= N) return;
  int rs = rowptr[node], re = rowptr[node + 1];
  float xself = hin[(long long)node * 64 + lane];
  float agg = 0.f;
  for (int cb = rs; cb < re; cb += 64) {
    int sidx = 0;
    if (cb + lane < re) sidx = clampN(colbuf[cb + lane], N);
    int c = re - cb;
    if (c > 64) c = 64;
    for (int t = 0; t < c; ++t) {
      int s = __builtin_amdgcn_readlane(sidx, t);
      agg += hin[(long long)s * 64 + lane];
    }
  }
  int deg = re - rs;
  if (deg > 0) agg *= (1.f / (float)deg);

  float o = ldf<BF>(bl, lane);
#pragma unroll 8
  for (int d = 0; d < 64; ++d) {
    float ad = __uint_as_float(
        __builtin_amdgcn_readlane(__float_as_uint(agg), d));
    float xd = __uint_as_float(
        __builtin_amdgcn_readlane(__float_as_uint(xself), d));
    o += ad * ldf<BF>(Wl, d * 64 + lane);
    o += xd * ldf<BF>(Wr, d * 64 + lane);
  }
  o = fmaxf(o, 0.f);

  if (!last) {
    hout[(long long)node * 64 + lane] = o;
  } else {
    float c0 = o * ldf<BF>(Wo, lane * 2 + 0);
    float c1 = o * ldf<BF>(Wo, lane * 2 + 1);
    for (int off = 32; off > 0; off >>= 1) {
      c0 += __shfl_xor(c0, off, 64);
      c1 += __shfl_xor(c1, off, 64);
    }
    if (lane == 0) {
      float r0 = c0 + ldf<BF>(bo, 0);
      float r1 = c1 + ldf<BF>(bo, 1);
      if (BF) {
        unsigned short* o16 = (unsigned short*)outp;
        o16[(long long)node * 2 + 0] = f2bf(r0);
        o16[(long long)node * 2 + 1] = f2bf(r1);
      } else {
        float* o32 = (float*)outp;
        o32[(long long)node * 2 + 0] = r0;
        o32[(long long)node * 2 + 1] = r1;
      }
    }
  }
}

__global__ __launch_bounds__(256) void k_layer(
    const float* hin, const int* rowptr, const int* colbuf, const void* Wl,
    const void* bl, const void* Wr, float* hout, int N, int last,
    const void* Wo, const void* bo, void* outp, const int* __restrict__ flags) {
  if (flags[0])
    layer_body<true>(hin, rowptr, colbuf, Wl, bl, Wr, hout, N, last, Wo, bo,
                     outp);
  else
    layer_body<false>(hin, rowptr, colbuf, Wl, bl, Wr, hout, N, last, Wo, bo,
                      outp);
}

// ---------------- host ----------------

extern "C" void kernel_launch(void* const* d_in, const int* in_sizes, int n_in,
                              void* d_out, int out_size, void* d_ws,
                              size_t ws_size, hipStream_t stream) {
  const void* xc = d_in[0];
  const void* xs = d_in[1];
  const int* ei = (const int*)d_in[2];
  const void* Wp = d_in[4];
  const void* bp = d_in[5];
  const void* Ws = d_in[6];
  const void* bs = d_in[7];
  const void* Wl1 = d_in[8];
  const void* bl1 = d_in[9];
  const void* Wr1 = d_in[10];
  const void* Wl2 = d_in[11];
  const void* bl2 = d_in[12];
  const void* Wr2 = d_in[13];
  const void* Wl3 = d_in[14];
  const void* bl3 = d_in[15];
  const void* Wr3 = d_in[16];
  const void* Wo = d_in[17];
  const void* bo = d_in[18];

  int N = out_size / 2;   // output is [N, 2]
  int E = in_sizes[3];    // edge_type has E elements

  char* ws = (char*)d_ws;
  size_t off = 0;
  auto alloc = [&](size_t bytes) {
    char* p = ws + off;
    off += (bytes + 255) & ~(size_t)255;
    return p;
  };
  int* colbuf = (int*)alloc((size_t)E * 4);
  int* cnt = (int*)alloc((size_t)N * 4);
  int* rowptr = (int*)alloc((size_t)(N + 1) * 4);
  int* cursor = (int*)alloc((size_t)N * 4);
  int* bsum = (int*)alloc(4096);
  int* flags = (int*)alloc(256);
  float* h0 = (float*)alloc((size_t)N * 64 * 4);
  float* h1 = (float*)alloc((size_t)N * 64 * 4);
  (void)ws_size;
  (void)n_in;

  k_detect<<<1, 64, 0, stream>>>(Wp, ei, flags);

  hipMemsetAsync(cnt, 0, (size_t)N * 4, stream);
  int eb = (E + 255) / 256;
  k_deg<<<eb, 256, 0, stream>>>(ei, E, N, cnt, flags);
  int sb = (N + 1023) / 1024;
  k_scan1<<<sb, 256, 0, stream>>>(cnt, rowptr, bsum, N);
  k_scan2<<<1, 64, 0, stream>>>(bsum, sb, rowptr, N);
  k_scan3<<<(N + 255) / 256, 256, 0, stream>>>(rowptr, cursor, bsum, N);
  k_scatter<<<eb, 256, 0, stream>>>(ei, E, N, cursor, colbuf, flags);

  int pb = (N + 63) / 64;  // one 64-thread block = 64 nodes
  k_project<<<pb, 64, 0, stream>>>(xc, xs, Wp, bp, Ws, bs, h0, N, flags);

  int nb4 = (N + 3) / 4;  // 4 waves (nodes) per 256-thread block
  k_layer<<<nb4, 256, 0, stream>>>(h0, rowptr, colbuf, Wl1, bl1, Wr1, h1, N, 0,
                                   nullptr, nullptr, nullptr, flags);
  k_layer<<<nb4, 256, 0, stream>>>(h1, rowptr, colbuf, Wl2, bl2, Wr2, h0, N, 0,
                                   nullptr, nullptr, nullptr, flags);
  k_layer<<<nb4, 256, 0, stream>>>(h0, rowptr, colbuf, Wl3, bl3, Wr3, h1, N, 1,
                                   Wo, bo, d_out, flags);
}

// Round 2
// 932.825 us; speedup vs baseline: 1.2968x; 1.0885x over previous
//
#include <hip/hip_runtime.h>
#include <stdint.h>

// ---------------------------------------------------------------------------
// FakeNewsModel: 3-layer GraphSAGE (mean agg), N=50000, E=1.6M, width 64.
// Round 5: k_project v4 — fix grid starvation (round-4 occupancy was 9%:
// 782 waves total, 0.76/SIMD, pure latency-bound at 267us / 10% VALUBusy).
// New decomposition: 256-thread block = 4 waves over 64 nodes; wave w owns
// output-quarter w (8 content + 8 style cols). Out-split is wave-uniform
// (readfirstlane) so W row-quarter loads stay SCALAR (s_load). x rows are
// re-read x4 by the 4 waves of a block -> L1/L2 absorbs. 2-chunk-deep x
// pipeline (32 elems in flight/thread). Everything else identical.
//   k_detect  -> flags[0]=floats-are-bf16?, flags[1]=ints-are-int64?
//   CSR build -> memset(cnt), k_deg, k_scan1/2/3, k_scatter
//   k_project -> x0 = concat(xc@Wp+bp, xs@Ws+bs)  (fp32 h-table)
//   k_layer x3 -> relu(mean-agg@Wl + bl + x@Wr); layer 3 fuses [64,2] head.
// ---------------------------------------------------------------------------

typedef __attribute__((ext_vector_type(8))) unsigned short u16x8;
typedef __attribute__((ext_vector_type(4))) float f32x4;

static __device__ __forceinline__ float bf2f(unsigned short u) {
  union { unsigned int i; float f; } v;
  v.i = ((unsigned int)u) << 16;
  return v.f;
}

static __device__ __forceinline__ unsigned short f2bf(float f) {
  union { float f; unsigned int i; } v;
  v.f = f;
  unsigned int u = v.i;
  unsigned int r = (u + 0x7FFFu + ((u >> 16) & 1u)) >> 16;  // RNE
  return (unsigned short)r;
}

template <bool BF>
static __device__ __forceinline__ float ldf(const void* p, long long i) {
  if (BF) return bf2f(((const unsigned short*)p)[i]);
  return ((const float*)p)[i];
}

// 8 consecutive floats starting at element idx (16B-aligned in bf16 world).
template <bool BF>
static __device__ __forceinline__ void load8(const void* p, long long idx,
                                             float* out) {
  if (BF) {
    u16x8 v = *(const u16x8*)((const unsigned short*)p + idx);
#pragma unroll
    for (int j = 0; j < 8; ++j) out[j] = bf2f(v[j]);
  } else {
    f32x4 a = *(const f32x4*)((const float*)p + idx);
    f32x4 b = *(const f32x4*)((const float*)p + idx + 4);
#pragma unroll
    for (int j = 0; j < 4; ++j) {
      out[j] = a[j];
      out[4 + j] = b[j];
    }
  }
}

// 8 consecutive W values: row `row`, columns [8*q, 8*q+8) of a [K,32] matrix.
// row and q are wave-uniform -> compiler emits scalar (s_load) loads.
template <bool BF>
static __device__ __forceinline__ void loadw8q(const void* p, int row, int q,
                                               float* wv) {
  if (BF) {
    const unsigned int* d = (const unsigned int*)p + row * 16 + q * 4;
#pragma unroll
    for (int t = 0; t < 4; ++t) {
      unsigned int u = d[t];
      union { unsigned int i; float f; } c0, c1;
      c0.i = u << 16;
      c1.i = u & 0xFFFF0000u;
      wv[2 * t + 0] = c0.f;
      wv[2 * t + 1] = c1.f;
    }
  } else {
    const float* d = (const float*)p + row * 32 + q * 8;
#pragma unroll
    for (int t = 0; t < 8; ++t) wv[t] = d[t];
  }
}

static __device__ __forceinline__ int clampN(int v, int N) {
  return v < 0 ? 0 : (v >= N ? N - 1 : v);
}

// ---------------- dtype detection ----------------
__global__ void k_detect(const void* Wp, const int* ei, int* flags) {
  if (threadIdx.x == 0 && blockIdx.x == 0) {
    const unsigned short* w = (const unsigned short*)Wp;
    int bf = 1;
    for (int i = 0; i < 64; ++i) {
      float v = fabsf(bf2f(w[i]));
      if (!(v < 1.0f)) bf = 0;  // catches NaN too
    }
    flags[0] = bf;
    int i64 = 1;
    for (int i = 0; i < 32; ++i)
      if (ei[2 * i + 1] != 0) i64 = 0;
    flags[1] = i64;
  }
}

static __device__ __forceinline__ int edge_src(const int* ei, int e, int E,
                                               int i64) {
  return i64 ? ei[2 * (long long)e] : ei[e];
}
static __device__ __forceinline__ int edge_dst(const int* ei, int e, int E,
                                               int i64) {
  return i64 ? ei[2 * ((long long)E + e)] : ei[(long long)E + e];
}

// ---------------- CSR build ----------------

__global__ __launch_bounds__(256) void k_deg(const int* __restrict__ ei, int E,
                                             int N, int* __restrict__ cnt,
                                             const int* __restrict__ flags) {
  int e = blockIdx.x * 256 + threadIdx.x;
  if (e < E) {
    int d = clampN(edge_dst(ei, e, E, flags[1]), N);
    atomicAdd(&cnt[d], 1);
  }
}

__global__ __launch_bounds__(256) void k_scan1(const int* __restrict__ cnt,
                                               int* __restrict__ rowptr,
                                               int* __restrict__ bsum, int N) {
  __shared__ int sh[256];
  int t = threadIdx.x;
  int base = blockIdx.x * 1024 + t * 4;
  int v0 = 0, v1 = 0, v2 = 0, v3 = 0;
  if (base + 0 < N) v0 = cnt[base + 0];
  if (base + 1 < N) v1 = cnt[base + 1];
  if (base + 2 < N) v2 = cnt[base + 2];
  if (base + 3 < N) v3 = cnt[base + 3];
  int s = v0 + v1 + v2 + v3;
  sh[t] = s;
  __syncthreads();
  int acc = s;
  for (int off = 1; off < 256; off <<= 1) {
    int x = 0;
    if (t >= off) x = sh[t - off];
    __syncthreads();
    acc += x;
    sh[t] = acc;
    __syncthreads();
  }
  int run = acc - s;
  if (base + 0 < N) rowptr[base + 0] = run;
  run += v0;
  if (base + 1 < N) rowptr[base + 1] = run;
  run += v1;
  if (base + 2 < N) rowptr[base + 2] = run;
  run += v2;
  if (base + 3 < N) rowptr[base + 3] = run;
  run += v3;
  if (t == 255) bsum[blockIdx.x] = acc;
}

__global__ void k_scan2(int* __restrict__ bsum, int nb,
                        int* __restrict__ rowptr, int N) {
  if (threadIdx.x == 0 && blockIdx.x == 0) {
    int run = 0;
    for (int i = 0; i < nb; ++i) {
      int v = bsum[i];
      bsum[i] = run;
      run += v;
    }
    rowptr[N] = run;
  }
}

__global__ __launch_bounds__(256) void k_scan3(int* __restrict__ rowptr,
                                               int* __restrict__ cursor,
                                               const int* __restrict__ bsum,
                                               int N) {
  int i = blockIdx.x * 256 + threadIdx.x;
  if (i < N) {
    int v = rowptr[i] + bsum[i >> 10];
    rowptr[i] = v;
    cursor[i] = v;
  }
}

__global__ __launch_bounds__(256) void k_scatter(const int* __restrict__ ei,
                                                 int E, int N,
                                                 int* __restrict__ cursor,
                                                 int* __restrict__ colbuf,
                                                 const int* __restrict__ flags) {
  int e = blockIdx.x * 256 + threadIdx.x;
  if (e < E) {
    int i64 = flags[1];
    int s = clampN(edge_src(ei, e, E, i64), N);
    int d = clampN(edge_dst(ei, e, E, i64), N);
    int p = atomicAdd(&cursor[d], 1);
    if (p >= 0 && p < E) colbuf[p] = s;
  }
}

// ---------------- projection (v4: wave-split outputs, scalar W loads) -------
// Block = 256 threads = 4 waves over 64 nodes. Wave w computes output columns
// [8w, 8w+8) of content AND of style for its 64 nodes. The column quarter is
// wave-uniform -> W row-quarter loads are scalar (s_load_dwordx4). Each
// thread keeps only 16 fp32 accumulators. x is read in 16-element chunks with
// a 2-chunk software pipeline (32 floats in flight per thread).
template <bool BF>
static __device__ void project_body(const void* __restrict__ xc,
                                    const void* __restrict__ xs,
                                    const void* __restrict__ Wp,
                                    const void* __restrict__ bp,
                                    const void* __restrict__ Ws,
                                    const void* __restrict__ bs,
                                    float* __restrict__ h0, int N) {
  int tid = (int)threadIdx.x;
  int w = __builtin_amdgcn_readfirstlane(tid >> 6);  // out-quarter 0..3
  int lane = tid & 63;
  int node = (int)blockIdx.x * 64 + lane;
  int nclamp = node < N ? node : (N - 1);

  float accc[8], accs[8];
#pragma unroll
  for (int r = 0; r < 8; ++r) {
    accc[r] = ldf<BF>(bp, 8 * w + r);
    accs[r] = ldf<BF>(bs, 8 * w + r);
  }

  // ---- content: x[768] dot Wp[768, 8w..8w+8) ----
  {
    long long xoff = (long long)nclamp * 768;
    float a0[8], a1[8], n0[8], n1[8];
    load8<BF>(xc, xoff + 0, a0);
    load8<BF>(xc, xoff + 8, a1);
#pragma unroll 1
    for (int k = 0; k < 768; k += 16) {
      int k2 = (k + 16 < 768) ? (k + 16) : 0;  // always-valid prefetch addr
      load8<BF>(xs == xs ? xc : xc, xoff + k2, n0);  // plain prefetch
      load8<BF>(xc, xoff + k2 + 8, n1);
#pragma unroll
      for (int j = 0; j < 8; ++j) {
        float wv[8];
        loadw8q<BF>(Wp, k + j, w, wv);
#pragma unroll
        for (int r = 0; r < 8; ++r) accc[r] += a0[j] * wv[r];
      }
#pragma unroll
      for (int j = 0; j < 8; ++j) {
        float wv[8];
        loadw8q<BF>(Wp, k + 8 + j, w, wv);
#pragma unroll
        for (int r = 0; r < 8; ++r) accc[r] += a1[j] * wv[r];
      }
#pragma unroll
      for (int j = 0; j < 8; ++j) {
        a0[j] = n0[j];
        a1[j] = n1[j];
      }
    }
  }

  // ---- style: x[128] dot Ws[128, 8w..8w+8) ----
  {
    long long soff = (long long)nclamp * 128;
    float a0[8], a1[8], n0[8], n1[8];
    load8<BF>(xs, soff + 0, a0);
    load8<BF>(xs, soff + 8, a1);
#pragma unroll 1
    for (int k = 0; k < 128; k += 16) {
      int k2 = (k + 16 < 128) ? (k + 16) : 0;
      load8<BF>(xs, soff + k2, n0);
      load8<BF>(xs, soff + k2 + 8, n1);
#pragma unroll
      for (int j = 0; j < 8; ++j) {
        float wv[8];
        loadw8q<BF>(Ws, k + j, w, wv);
#pragma unroll
        for (int r = 0; r < 8; ++r) accs[r] += a0[j] * wv[r];
      }
#pragma unroll
      for (int j = 0; j < 8; ++j) {
        float wv[8];
        loadw8q<BF>(Ws, k + 8 + j, w, wv);
#pragma unroll
        for (int r = 0; r < 8; ++r) accs[r] += a1[j] * wv[r];
      }
#pragma unroll
      for (int j = 0; j < 8; ++j) {
        a0[j] = n0[j];
        a1[j] = n1[j];
      }
    }
  }

  if (node < N) {
    float* orow = h0 + (long long)node * 64;
    f32x4 v;
#pragma unroll
    for (int r = 0; r < 4; ++r) v[r] = accc[r];
    *(f32x4*)(orow + 8 * w) = v;
#pragma unroll
    for (int r = 0; r < 4; ++r) v[r] = accc[4 + r];
    *(f32x4*)(orow + 8 * w + 4) = v;
#pragma unroll
    for (int r = 0; r < 4; ++r) v[r] = accs[r];
    *(f32x4*)(orow + 32 + 8 * w) = v;
#pragma unroll
    for (int r = 0; r < 4; ++r) v[r] = accs[4 + r];
    *(f32x4*)(orow + 32 + 8 * w + 4) = v;
  }
}

__global__ __launch_bounds__(256) void k_project(
    const void* __restrict__ xc, const void* __restrict__ xs,
    const void* __restrict__ Wp, const void* __restrict__ bp,
    const void* __restrict__ Ws, const void* __restrict__ bs,
    float* __restrict__ h0, int N, const int* __restrict__ flags) {
  if (flags[0])
    project_body<true>(xc, xs, Wp, bp, Ws, bs, h0, N);
  else
    project_body<false>(xc, xs, Wp, bp, Ws, bs, h0, N);
}

// ---------------- SAGE layer ----------------
template <bool BF>
static __device__ void layer_body(const float* __restrict__ hin,
                                  const int* __restrict__ rowptr,
                                  const int* __restrict__ colbuf,
                                  const void* Wl, const void* bl,
                                  const void* Wr, float* __restrict__ hout,
                                  int N, int last, const void* Wo,
                                  const void* bo, void* outp) {
  int node = (int)((blockIdx.x * blockDim.x + threadIdx.x) >> 6);
  int lane = (int)(threadIdx.x & 63);
  if (node >= N) return;
  int rs = rowptr[node], re = rowptr[node + 1];
  float xself = hin[(long long)node * 64 + lane];
  float agg = 0.f;
  for (int cb = rs; cb < re; cb += 64) {
    int sidx = 0;
    if (cb + lane < re) sidx = clampN(colbuf[cb + lane], N);
    int c = re - cb;
    if (c > 64) c = 64;
    for (int t = 0; t < c; ++t) {
      int s = __builtin_amdgcn_readlane(sidx, t);
      agg += hin[(long long)s * 64 + lane];
    }
  }
  int deg = re - rs;
  if (deg > 0) agg *= (1.f / (float)deg);

  float o = ldf<BF>(bl, lane);
#pragma unroll 8
  for (int d = 0; d < 64; ++d) {
    float ad = __uint_as_float(
        __builtin_amdgcn_readlane(__float_as_uint(agg), d));
    float xd = __uint_as_float(
        __builtin_amdgcn_readlane(__float_as_uint(xself), d));
    o += ad * ldf<BF>(Wl, d * 64 + lane);
    o += xd * ldf<BF>(Wr, d * 64 + lane);
  }
  o = fmaxf(o, 0.f);

  if (!last) {
    hout[(long long)node * 64 + lane] = o;
  } else {
    float c0 = o * ldf<BF>(Wo, lane * 2 + 0);
    float c1 = o * ldf<BF>(Wo, lane * 2 + 1);
    for (int off = 32; off > 0; off >>= 1) {
      c0 += __shfl_xor(c0, off, 64);
      c1 += __shfl_xor(c1, off, 64);
    }
    if (lane == 0) {
      float r0 = c0 + ldf<BF>(bo, 0);
      float r1 = c1 + ldf<BF>(bo, 1);
      if (BF) {
        unsigned short* o16 = (unsigned short*)outp;
        o16[(long long)node * 2 + 0] = f2bf(r0);
        o16[(long long)node * 2 + 1] = f2bf(r1);
      } else {
        float* o32 = (float*)outp;
        o32[(long long)node * 2 + 0] = r0;
        o32[(long long)node * 2 + 1] = r1;
      }
    }
  }
}

__global__ __launch_bounds__(256) void k_layer(
    const float* hin, const int* rowptr, const int* colbuf, const void* Wl,
    const void* bl, const void* Wr, float* hout, int N, int last,
    const void* Wo, const void* bo, void* outp, const int* __restrict__ flags) {
  if (flags[0])
    layer_body<true>(hin, rowptr, colbuf, Wl, bl, Wr, hout, N, last, Wo, bo,
                     outp);
  else
    layer_body<false>(hin, rowptr, colbuf, Wl, bl, Wr, hout, N, last, Wo, bo,
                      outp);
}

// ---------------- host ----------------

extern "C" void kernel_launch(void* const* d_in, const int* in_sizes, int n_in,
                              void* d_out, int out_size, void* d_ws,
                              size_t ws_size, hipStream_t stream) {
  const void* xc = d_in[0];
  const void* xs = d_in[1];
  const int* ei = (const int*)d_in[2];
  const void* Wp = d_in[4];
  const void* bp = d_in[5];
  const void* Ws = d_in[6];
  const void* bs = d_in[7];
  const void* Wl1 = d_in[8];
  const void* bl1 = d_in[9];
  const void* Wr1 = d_in[10];
  const void* Wl2 = d_in[11];
  const void* bl2 = d_in[12];
  const void* Wr2 = d_in[13];
  const void* Wl3 = d_in[14];
  const void* bl3 = d_in[15];
  const void* Wr3 = d_in[16];
  const void* Wo = d_in[17];
  const void* bo = d_in[18];

  int N = out_size / 2;   // output is [N, 2]
  int E = in_sizes[3];    // edge_type has E elements

  char* ws = (char*)d_ws;
  size_t off = 0;
  auto alloc = [&](size_t bytes) {
    char* p = ws + off;
    off += (bytes + 255) & ~(size_t)255;
    return p;
  };
  int* colbuf = (int*)alloc((size_t)E * 4);
  int* cnt = (int*)alloc((size_t)N * 4);
  int* rowptr = (int*)alloc((size_t)(N + 1) * 4);
  int* cursor = (int*)alloc((size_t)N * 4);
  int* bsum = (int*)alloc(4096);
  int* flags = (int*)alloc(256);
  float* h0 = (float*)alloc((size_t)N * 64 * 4);
  float* h1 = (float*)alloc((size_t)N * 64 * 4);
  (void)ws_size;
  (void)n_in;

  k_detect<<<1, 64, 0, stream>>>(Wp, ei, flags);

  hipMemsetAsync(cnt, 0, (size_t)N * 4, stream);
  int eb = (E + 255) / 256;
  k_deg<<<eb, 256, 0, stream>>>(ei, E, N, cnt, flags);
  int sb = (N + 1023) / 1024;
  k_scan1<<<sb, 256, 0, stream>>>(cnt, rowptr, bsum, N);
  k_scan2<<<1, 64, 0, stream>>>(bsum, sb, rowptr, N);
  k_scan3<<<(N + 255) / 256, 256, 0, stream>>>(rowptr, cursor, bsum, N);
  k_scatter<<<eb, 256, 0, stream>>>(ei, E, N, cursor, colbuf, flags);

  int pb = (N + 63) / 64;  // 64 nodes per 256-thread block (4 waves, out-split)
  k_project<<<pb, 256, 0, stream>>>(xc, xs, Wp, bp, Ws, bs, h0, N, flags);

  int nb4 = (N + 3) / 4;  // 4 waves (nodes) per 256-thread block
  k_layer<<<nb4, 256, 0, stream>>>(h0, rowptr, colbuf, Wl1, bl1, Wr1, h1, N, 0,
                                   nullptr, nullptr, nullptr, flags);
  k_layer<<<nb4, 256, 0, stream>>>(h1, rowptr, colbuf, Wl2, bl2, Wr2, h0, N, 0,
                                   nullptr, nullptr, nullptr, flags);
  k_layer<<<nb4, 256, 0, stream>>>(h0, rowptr, colbuf, Wl3, bl3, Wr3, h1, N, 1,
                                   Wo, bo, d_out, flags);
}

// Round 3
// 794.363 us; speedup vs baseline: 1.5228x; 1.1743x over previous
//
#include <hip/hip_runtime.h>
#include <stdint.h>

// ---------------------------------------------------------------------------
// FakeNewsModel: 3-layer GraphSAGE (mean agg), N=50000, E=1.6M, width 64.
// Round 6: k_project v5 — K-split across waves. Round-5 was still latency
// bound (184us, VALUBusy 12%, occ 27%): 3.05 waves/SIMD each walking 56
// serial k-iterations. Now: 512-thread block = 8 waves over 64 nodes; wave
// (q,h) computes out-quarter q over K-half h. 2x waves (24/CU) x half the
// chain (28 iters). Partials combined via padded LDS (stride 65 -> 2-way
// conflicts only = free). W loads stay scalar (row wave-uniform).
// k_layer: gather loop unrolled x4 into independent accumulators (4 loads in
// flight, 1/4 dep-chain depth). Everything else identical.
//   k_detect  -> flags[0]=floats-are-bf16?, flags[1]=ints-are-int64?
//   CSR build -> memset(cnt), k_deg, k_scan1/2/3, k_scatter
//   k_project -> x0 = concat(xc@Wp+bp, xs@Ws+bs)  (fp32 h-table)
//   k_layer x3 -> relu(mean-agg@Wl + bl + x@Wr); layer 3 fuses [64,2] head.
// ---------------------------------------------------------------------------

typedef __attribute__((ext_vector_type(8))) unsigned short u16x8;
typedef __attribute__((ext_vector_type(4))) float f32x4;

static __device__ __forceinline__ float bf2f(unsigned short u) {
  union { unsigned int i; float f; } v;
  v.i = ((unsigned int)u) << 16;
  return v.f;
}

static __device__ __forceinline__ unsigned short f2bf(float f) {
  union { float f; unsigned int i; } v;
  v.f = f;
  unsigned int u = v.i;
  unsigned int r = (u + 0x7FFFu + ((u >> 16) & 1u)) >> 16;  // RNE
  return (unsigned short)r;
}

template <bool BF>
static __device__ __forceinline__ float ldf(const void* p, long long i) {
  if (BF) return bf2f(((const unsigned short*)p)[i]);
  return ((const float*)p)[i];
}

// 8 consecutive floats starting at element idx (16B-aligned in bf16 world).
template <bool BF>
static __device__ __forceinline__ void load8(const void* p, long long idx,
                                             float* out) {
  if (BF) {
    u16x8 v = *(const u16x8*)((const unsigned short*)p + idx);
#pragma unroll
    for (int j = 0; j < 8; ++j) out[j] = bf2f(v[j]);
  } else {
    f32x4 a = *(const f32x4*)((const float*)p + idx);
    f32x4 b = *(const f32x4*)((const float*)p + idx + 4);
#pragma unroll
    for (int j = 0; j < 4; ++j) {
      out[j] = a[j];
      out[4 + j] = b[j];
    }
  }
}

// 8 consecutive W values: row `row`, columns [8*q, 8*q+8) of a [K,32] matrix.
// row and q are wave-uniform -> compiler emits scalar (s_load) loads.
template <bool BF>
static __device__ __forceinline__ void loadw8q(const void* p, int row, int q,
                                               float* wv) {
  if (BF) {
    const unsigned int* d = (const unsigned int*)p + row * 16 + q * 4;
#pragma unroll
    for (int t = 0; t < 4; ++t) {
      unsigned int u = d[t];
      union { unsigned int i; float f; } c0, c1;
      c0.i = u << 16;
      c1.i = u & 0xFFFF0000u;
      wv[2 * t + 0] = c0.f;
      wv[2 * t + 1] = c1.f;
    }
  } else {
    const float* d = (const float*)p + row * 32 + q * 8;
#pragma unroll
    for (int t = 0; t < 8; ++t) wv[t] = d[t];
  }
}

static __device__ __forceinline__ int clampN(int v, int N) {
  return v < 0 ? 0 : (v >= N ? N - 1 : v);
}

// ---------------- dtype detection ----------------
__global__ void k_detect(const void* Wp, const int* ei, int* flags) {
  if (threadIdx.x == 0 && blockIdx.x == 0) {
    const unsigned short* w = (const unsigned short*)Wp;
    int bf = 1;
    for (int i = 0; i < 64; ++i) {
      float v = fabsf(bf2f(w[i]));
      if (!(v < 1.0f)) bf = 0;  // catches NaN too
    }
    flags[0] = bf;
    int i64 = 1;
    for (int i = 0; i < 32; ++i)
      if (ei[2 * i + 1] != 0) i64 = 0;
    flags[1] = i64;
  }
}

static __device__ __forceinline__ int edge_src(const int* ei, int e, int E,
                                               int i64) {
  return i64 ? ei[2 * (long long)e] : ei[e];
}
static __device__ __forceinline__ int edge_dst(const int* ei, int e, int E,
                                               int i64) {
  return i64 ? ei[2 * ((long long)E + e)] : ei[(long long)E + e];
}

// ---------------- CSR build ----------------

__global__ __launch_bounds__(256) void k_deg(const int* __restrict__ ei, int E,
                                             int N, int* __restrict__ cnt,
                                             const int* __restrict__ flags) {
  int e = blockIdx.x * 256 + threadIdx.x;
  if (e < E) {
    int d = clampN(edge_dst(ei, e, E, flags[1]), N);
    atomicAdd(&cnt[d], 1);
  }
}

__global__ __launch_bounds__(256) void k_scan1(const int* __restrict__ cnt,
                                               int* __restrict__ rowptr,
                                               int* __restrict__ bsum, int N) {
  __shared__ int sh[256];
  int t = threadIdx.x;
  int base = blockIdx.x * 1024 + t * 4;
  int v0 = 0, v1 = 0, v2 = 0, v3 = 0;
  if (base + 0 < N) v0 = cnt[base + 0];
  if (base + 1 < N) v1 = cnt[base + 1];
  if (base + 2 < N) v2 = cnt[base + 2];
  if (base + 3 < N) v3 = cnt[base + 3];
  int s = v0 + v1 + v2 + v3;
  sh[t] = s;
  __syncthreads();
  int acc = s;
  for (int off = 1; off < 256; off <<= 1) {
    int x = 0;
    if (t >= off) x = sh[t - off];
    __syncthreads();
    acc += x;
    sh[t] = acc;
    __syncthreads();
  }
  int run = acc - s;
  if (base + 0 < N) rowptr[base + 0] = run;
  run += v0;
  if (base + 1 < N) rowptr[base + 1] = run;
  run += v1;
  if (base + 2 < N) rowptr[base + 2] = run;
  run += v2;
  if (base + 3 < N) rowptr[base + 3] = run;
  run += v3;
  if (t == 255) bsum[blockIdx.x] = acc;
}

__global__ void k_scan2(int* __restrict__ bsum, int nb,
                        int* __restrict__ rowptr, int N) {
  if (threadIdx.x == 0 && blockIdx.x == 0) {
    int run = 0;
    for (int i = 0; i < nb; ++i) {
      int v = bsum[i];
      bsum[i] = run;
      run += v;
    }
    rowptr[N] = run;
  }
}

__global__ __launch_bounds__(256) void k_scan3(int* __restrict__ rowptr,
                                               int* __restrict__ cursor,
                                               const int* __restrict__ bsum,
                                               int N) {
  int i = blockIdx.x * 256 + threadIdx.x;
  if (i < N) {
    int v = rowptr[i] + bsum[i >> 10];
    rowptr[i] = v;
    cursor[i] = v;
  }
}

__global__ __launch_bounds__(256) void k_scatter(const int* __restrict__ ei,
                                                 int E, int N,
                                                 int* __restrict__ cursor,
                                                 int* __restrict__ colbuf,
                                                 const int* __restrict__ flags) {
  int e = blockIdx.x * 256 + threadIdx.x;
  if (e < E) {
    int i64 = flags[1];
    int s = clampN(edge_src(ei, e, E, i64), N);
    int d = clampN(edge_dst(ei, e, E, i64), N);
    int p = atomicAdd(&cursor[d], 1);
    if (p >= 0 && p < E) colbuf[p] = s;
  }
}

// ---------------- projection (v5: K-split waves, scalar W loads) ------------
// Block = 512 threads = 8 waves over 64 nodes. Wave w -> (q = w&3, h = w>>2):
// computes output columns [8q, 8q+8) of content AND style over K-half h
// (content rows [384h, 384h+384), style rows [64h, 64h+64)). Column quarter
// and K-half are wave-uniform -> W loads are scalar (s_load). Partials meet
// in LDS red[2][64][65] (stride 65 -> bank = lane+out, conflict-free), then
// 512 threads combine + bias + coalesced f32x4 stores.
template <bool BF>
static __device__ void project_body(const void* __restrict__ xc,
                                    const void* __restrict__ xs,
                                    const void* __restrict__ Wp,
                                    const void* __restrict__ bp,
                                    const void* __restrict__ Ws,
                                    const void* __restrict__ bs,
                                    float* __restrict__ h0, int N) {
  __shared__ float red[2 * 64 * 65];
  int tid = (int)threadIdx.x;
  int w = __builtin_amdgcn_readfirstlane(tid >> 6);  // 0..7
  int q = w & 3;   // out-quarter
  int h = w >> 2;  // K-half
  int lane = tid & 63;
  int node = (int)blockIdx.x * 64 + lane;
  int nclamp = node < N ? node : (N - 1);

  float accc[8], accs[8];
#pragma unroll
  for (int r = 0; r < 8; ++r) {
    accc[r] = 0.f;
    accs[r] = 0.f;
  }

  // ---- content slice: x[384h .. 384h+384) dot Wp[rows, 8q..8q+8) ----
  {
    long long xoff = (long long)nclamp * 768 + h * 384;
    int rbase = h * 384;
    float a0[8], a1[8], n0[8], n1[8];
    load8<BF>(xc, xoff + 0, a0);
    load8<BF>(xc, xoff + 8, a1);
#pragma unroll 1
    for (int k = 0; k < 384; k += 16) {
      int k2 = (k + 16 < 384) ? (k + 16) : 0;  // always-valid prefetch addr
      load8<BF>(xc, xoff + k2, n0);
      load8<BF>(xc, xoff + k2 + 8, n1);
#pragma unroll
      for (int j = 0; j < 8; ++j) {
        float wv[8];
        loadw8q<BF>(Wp, rbase + k + j, q, wv);
#pragma unroll
        for (int r = 0; r < 8; ++r) accc[r] += a0[j] * wv[r];
      }
#pragma unroll
      for (int j = 0; j < 8; ++j) {
        float wv[8];
        loadw8q<BF>(Wp, rbase + k + 8 + j, q, wv);
#pragma unroll
        for (int r = 0; r < 8; ++r) accc[r] += a1[j] * wv[r];
      }
#pragma unroll
      for (int j = 0; j < 8; ++j) {
        a0[j] = n0[j];
        a1[j] = n1[j];
      }
    }
  }

  // ---- style slice: x[64h .. 64h+64) dot Ws[rows, 8q..8q+8) ----
  {
    long long soff = (long long)nclamp * 128 + h * 64;
    int rbase = h * 64;
    float a0[8], a1[8], n0[8], n1[8];
    load8<BF>(xs, soff + 0, a0);
    load8<BF>(xs, soff + 8, a1);
#pragma unroll 1
    for (int k = 0; k < 64; k += 16) {
      int k2 = (k + 16 < 64) ? (k + 16) : 0;
      load8<BF>(xs, soff + k2, n0);
      load8<BF>(xs, soff + k2 + 8, n1);
#pragma unroll
      for (int j = 0; j < 8; ++j) {
        float wv[8];
        loadw8q<BF>(Ws, rbase + k + j, q, wv);
#pragma unroll
        for (int r = 0; r < 8; ++r) accs[r] += a0[j] * wv[r];
      }
#pragma unroll
      for (int j = 0; j < 8; ++j) {
        float wv[8];
        loadw8q<BF>(Ws, rbase + k + 8 + j, q, wv);
#pragma unroll
        for (int r = 0; r < 8; ++r) accs[r] += a1[j] * wv[r];
      }
#pragma unroll
      for (int j = 0; j < 8; ++j) {
        a0[j] = n0[j];
        a1[j] = n1[j];
      }
    }
  }

  // ---- write partials to LDS: red[(h*64+lane)*65 + out] ----
  {
    float* row = red + (h * 64 + lane) * 65;
#pragma unroll
    for (int r = 0; r < 8; ++r) {
      row[8 * q + r] = accc[r];
      row[32 + 8 * q + r] = accs[r];
    }
  }
  __syncthreads();

  // ---- combine halves + bias, coalesced store ----
  {
    int n2 = tid >> 3;        // 0..63 (node within block)
    int oc = (tid & 7) * 8;   // 0,8,...,56
    int gnode = (int)blockIdx.x * 64 + n2;
    if (gnode < N) {
      float v[8];
#pragma unroll
      for (int i = 0; i < 8; ++i) {
        int out = oc + i;
        float b = (out < 32) ? ldf<BF>(bp, out) : ldf<BF>(bs, out - 32);
        v[i] = red[n2 * 65 + out] + red[(64 + n2) * 65 + out] + b;
      }
      float* orow = h0 + (long long)gnode * 64 + oc;
      f32x4 v0 = {v[0], v[1], v[2], v[3]};
      f32x4 v1 = {v[4], v[5], v[6], v[7]};
      *(f32x4*)orow = v0;
      *(f32x4*)(orow + 4) = v1;
    }
  }
}

__global__ __launch_bounds__(512) void k_project(
    const void* __restrict__ xc, const void* __restrict__ xs,
    const void* __restrict__ Wp, const void* __restrict__ bp,
    const void* __restrict__ Ws, const void* __restrict__ bs,
    float* __restrict__ h0, int N, const int* __restrict__ flags) {
  if (flags[0])
    project_body<true>(xc, xs, Wp, bp, Ws, bs, h0, N);
  else
    project_body<false>(xc, xs, Wp, bp, Ws, bs, h0, N);
}

// ---------------- SAGE layer ----------------
template <bool BF>
static __device__ void layer_body(const float* __restrict__ hin,
                                  const int* __restrict__ rowptr,
                                  const int* __restrict__ colbuf,
                                  const void* Wl, const void* bl,
                                  const void* Wr, float* __restrict__ hout,
                                  int N, int last, const void* Wo,
                                  const void* bo, void* outp) {
  int node = (int)((blockIdx.x * blockDim.x + threadIdx.x) >> 6);
  int lane = (int)(threadIdx.x & 63);
  if (node >= N) return;
  int rs = rowptr[node], re = rowptr[node + 1];
  float xself = hin[(long long)node * 64 + lane];
  float agg0 = 0.f, agg1 = 0.f, agg2 = 0.f, agg3 = 0.f;
  for (int cb = rs; cb < re; cb += 64) {
    int sidx = 0;
    if (cb + lane < re) sidx = clampN(colbuf[cb + lane], N);
    int c = re - cb;
    if (c > 64) c = 64;
    int t = 0;
    for (; t + 4 <= c; t += 4) {
      int s0 = __builtin_amdgcn_readlane(sidx, t + 0);
      int s1 = __builtin_amdgcn_readlane(sidx, t + 1);
      int s2 = __builtin_amdgcn_readlane(sidx, t + 2);
      int s3 = __builtin_amdgcn_readlane(sidx, t + 3);
      float v0 = hin[(long long)s0 * 64 + lane];
      float v1 = hin[(long long)s1 * 64 + lane];
      float v2 = hin[(long long)s2 * 64 + lane];
      float v3 = hin[(long long)s3 * 64 + lane];
      agg0 += v0;
      agg1 += v1;
      agg2 += v2;
      agg3 += v3;
    }
    for (; t < c; ++t) {
      int s = __builtin_amdgcn_readlane(sidx, t);
      agg0 += hin[(long long)s * 64 + lane];
    }
  }
  float agg = (agg0 + agg1) + (agg2 + agg3);
  int deg = re - rs;
  if (deg > 0) agg *= (1.f / (float)deg);

  float o = ldf<BF>(bl, lane);
#pragma unroll 8
  for (int d = 0; d < 64; ++d) {
    float ad = __uint_as_float(
        __builtin_amdgcn_readlane(__float_as_uint(agg), d));
    float xd = __uint_as_float(
        __builtin_amdgcn_readlane(__float_as_uint(xself), d));
    o += ad * ldf<BF>(Wl, d * 64 + lane);
    o += xd * ldf<BF>(Wr, d * 64 + lane);
  }
  o = fmaxf(o, 0.f);

  if (!last) {
    hout[(long long)node * 64 + lane] = o;
  } else {
    float c0 = o * ldf<BF>(Wo, lane * 2 + 0);
    float c1 = o * ldf<BF>(Wo, lane * 2 + 1);
    for (int off = 32; off > 0; off >>= 1) {
      c0 += __shfl_xor(c0, off, 64);
      c1 += __shfl_xor(c1, off, 64);
    }
    if (lane == 0) {
      float r0 = c0 + ldf<BF>(bo, 0);
      float r1 = c1 + ldf<BF>(bo, 1);
      if (BF) {
        unsigned short* o16 = (unsigned short*)outp;
        o16[(long long)node * 2 + 0] = f2bf(r0);
        o16[(long long)node * 2 + 1] = f2bf(r1);
      } else {
        float* o32 = (float*)outp;
        o32[(long long)node * 2 + 0] = r0;
        o32[(long long)node * 2 + 1] = r1;
      }
    }
  }
}

__global__ __launch_bounds__(256) void k_layer(
    const float* hin, const int* rowptr, const int* colbuf, const void* Wl,
    const void* bl, const void* Wr, float* hout, int N, int last,
    const void* Wo, const void* bo, void* outp, const int* __restrict__ flags) {
  if (flags[0])
    layer_body<true>(hin, rowptr, colbuf, Wl, bl, Wr, hout, N, last, Wo, bo,
                     outp);
  else
    layer_body<false>(hin, rowptr, colbuf, Wl, bl, Wr, hout, N, last, Wo, bo,
                      outp);
}

// ---------------- host ----------------

extern "C" void kernel_launch(void* const* d_in, const int* in_sizes, int n_in,
                              void* d_out, int out_size, void* d_ws,
                              size_t ws_size, hipStream_t stream) {
  const void* xc = d_in[0];
  const void* xs = d_in[1];
  const int* ei = (const int*)d_in[2];
  const void* Wp = d_in[4];
  const void* bp = d_in[5];
  const void* Ws = d_in[6];
  const void* bs = d_in[7];
  const void* Wl1 = d_in[8];
  const void* bl1 = d_in[9];
  const void* Wr1 = d_in[10];
  const void* Wl2 = d_in[11];
  const void* bl2 = d_in[12];
  const void* Wr2 = d_in[13];
  const void* Wl3 = d_in[14];
  const void* bl3 = d_in[15];
  const void* Wr3 = d_in[16];
  const void* Wo = d_in[17];
  const void* bo = d_in[18];

  int N = out_size / 2;   // output is [N, 2]
  int E = in_sizes[3];    // edge_type has E elements

  char* ws = (char*)d_ws;
  size_t off = 0;
  auto alloc = [&](size_t bytes) {
    char* p = ws + off;
    off += (bytes + 255) & ~(size_t)255;
    return p;
  };
  int* colbuf = (int*)alloc((size_t)E * 4);
  int* cnt = (int*)alloc((size_t)N * 4);
  int* rowptr = (int*)alloc((size_t)(N + 1) * 4);
  int* cursor = (int*)alloc((size_t)N * 4);
  int* bsum = (int*)alloc(4096);
  int* flags = (int*)alloc(256);
  float* h0 = (float*)alloc((size_t)N * 64 * 4);
  float* h1 = (float*)alloc((size_t)N * 64 * 4);
  (void)ws_size;
  (void)n_in;

  k_detect<<<1, 64, 0, stream>>>(Wp, ei, flags);

  hipMemsetAsync(cnt, 0, (size_t)N * 4, stream);
  int eb = (E + 255) / 256;
  k_deg<<<eb, 256, 0, stream>>>(ei, E, N, cnt, flags);
  int sb = (N + 1023) / 1024;
  k_scan1<<<sb, 256, 0, stream>>>(cnt, rowptr, bsum, N);
  k_scan2<<<1, 64, 0, stream>>>(bsum, sb, rowptr, N);
  k_scan3<<<(N + 255) / 256, 256, 0, stream>>>(rowptr, cursor, bsum, N);
  k_scatter<<<eb, 256, 0, stream>>>(ei, E, N, cursor, colbuf, flags);

  int pb = (N + 63) / 64;  // 64 nodes per 512-thread block (8 waves, K-split)
  k_project<<<pb, 512, 0, stream>>>(xc, xs, Wp, bp, Ws, bs, h0, N, flags);

  int nb4 = (N + 3) / 4;  // 4 waves (nodes) per 256-thread block
  k_layer<<<nb4, 256, 0, stream>>>(h0, rowptr, colbuf, Wl1, bl1, Wr1, h1, N, 0,
                                   nullptr, nullptr, nullptr, flags);
  k_layer<<<nb4, 256, 0, stream>>>(h1, rowptr, colbuf, Wl2, bl2, Wr2, h0, N, 0,
                                   nullptr, nullptr, nullptr, flags);
  k_layer<<<nb4, 256, 0, stream>>>(h0, rowptr, colbuf, Wl3, bl3, Wr3, h1, N, 1,
                                   Wo, bo, d_out, flags);
}